// Round 6
// baseline (192.434 us; speedup 1.0000x reference)
//
#include <hip/hip_runtime.h>
#include <hip/hip_bf16.h>
#include <stdint.h>

typedef __attribute__((ext_vector_type(8))) __bf16 bf16x8;
typedef __attribute__((ext_vector_type(4))) float  f32x4;
typedef __attribute__((ext_vector_type(16))) float f32x16;

__device__ __forceinline__ ushort f2bf(float f) {
    union { float f; uint32_t u; } v; v.f = f;
    uint32_t u = v.u;
    uint32_t r = 0x7FFFu + ((u >> 16) & 1u);
    return (ushort)((u + r) >> 16);
}
__device__ __forceinline__ float bf2f(ushort u) {
    union { uint32_t u; float f; } v; v.u = ((uint32_t)u) << 16;
    return v.f;
}
__device__ __forceinline__ unsigned packbf(float lo, float hi) {
    return (unsigned)f2bf(lo) | ((unsigned)f2bf(hi) << 16);
}

// async global->LDS, 16B per lane; LDS dest must be wave-uniform base + lane*16
typedef __attribute__((address_space(3))) uint32_t lds_u32_t;
typedef const __attribute__((address_space(1))) uint32_t glb_u32_t;
__device__ __forceinline__ void async_copy16(const void* g, void* l) {
    __builtin_amdgcn_global_load_lds((glb_u32_t*)g, (lds_u32_t*)l, 16, 0, 0);
}

// ------------- merged convert fp32 -> bf16: x then Wk,Wq,Wv -------------
__global__ __launch_bounds__(256) void convert_all(
    const float* __restrict__ x, const float* __restrict__ wk,
    const float* __restrict__ wq, const float* __restrict__ wv,
    ushort* __restrict__ xb, ushort* __restrict__ wball)
{
    int i = blockIdx.x * 256 + threadIdx.x;   // 1835008 float4 chunks total
    const float* src; ushort* dst; int j;
    if (i < 1048576) { src = x; dst = xb; j = i; }
    else {
        int t = i - 1048576;
        int z = t >> 18;             // 0..2
        j = t & 262143;
        src = (z == 0) ? wk : (z == 1) ? wq : wv;
        dst = wball + z * 1048576;
    }
    float4 f = ((const float4*)src)[j];
    ushort4 o;
    o.x = f2bf(f.x); o.y = f2bf(f.y); o.z = f2bf(f.z); o.w = f2bf(f.w);
    ((ushort4*)dst)[j] = o;
}

// ---------------- QKV projection GEMM: Y = X @ W^T + b ----------------
// 2-deep pipelined: BK=32, 3-deep LDS ring, raw s_barrier + counted
// s_waitcnt vmcnt(8) so 2 tiles of global_load_lds stay in flight.
// T1 XCD swizzle (768 blocks % 8 == 0, bijective): each XCD gets 96
// consecutive logical tiles = 3 (col,z) weight panels (768 KB, L2-resident)
// instead of all 24 (6 MB, L2-thrash).
__global__ __launch_bounds__(256) void proj_gemm(
    const ushort* __restrict__ xb, const ushort* __restrict__ wball,
    const float* __restrict__ bk, const float* __restrict__ bq, const float* __restrict__ bv,
    ushort* __restrict__ kd, ushort* __restrict__ qd, ushort* __restrict__ vd)
{
    __shared__ ushort As[3 * 128 * 32];   // 24 KB, 3-deep ring
    __shared__ ushort Bs[3 * 128 * 32];   // 24 KB
    const int b = blockIdx.x + 32 * (blockIdx.y + 8 * blockIdx.z);
    const int lb = (b & 7) * 96 + (b >> 3);          // XCD-contiguous remap
    const int z = lb >> 8;                            // 0..2
    const int row0 = (lb & 31) * 128;
    const int col0 = ((lb >> 5) & 7) * 128;
    const ushort* wb = wball + z * 1048576;
    const int tid = threadIdx.x;
    const int lane = tid & 63, wave = tid >> 6;
    const int quad = lane >> 4, m15 = lane & 15;
    const int wr = wave >> 1, wc = wave & 1;

    f32x4 acc[4][4];
    for (int i = 0; i < 4; i++)
        for (int j = 0; j < 4; j++) acc[i][j] = (f32x4){0.f, 0.f, 0.f, 0.f};

#define STAGE(BI, KK) do {                                                        \
        _Pragma("unroll")                                                         \
        for (int i_ = 0; i_ < 2; i_++) {                                          \
            int c_ = tid + i_ * 256;           /* 0..511 */                       \
            int r_ = c_ >> 2, cjp_ = c_ & 3;                                      \
            int cj_ = cjp_ ^ ((r_ >> 1) & 3);                                     \
            async_copy16(&xb[(row0 + r_) * 1024 + (KK) + cj_ * 8],                \
                         &As[(BI) * 4096 + c_ * 8]);                              \
            async_copy16(&wb[(col0 + r_) * 1024 + (KK) + cj_ * 8],                \
                         &Bs[(BI) * 4096 + c_ * 8]);                              \
        }                                                                         \
    } while (0)

#define COMPUTE(BI) do {                                                          \
        const ushort* a_ = &As[(BI) * 4096];                                      \
        const ushort* b_ = &Bs[(BI) * 4096];                                      \
        bf16x8 af[4], bfv[4];                                                     \
        _Pragma("unroll")                                                         \
        for (int fr = 0; fr < 4; fr++) {                                          \
            int row = wr * 64 + fr * 16 + m15;                                    \
            af[fr] = *(const bf16x8*)&a_[row * 32 + ((quad ^ ((row >> 1) & 3)) * 8)]; \
        }                                                                         \
        _Pragma("unroll")                                                         \
        for (int fc = 0; fc < 4; fc++) {                                          \
            int row = wc * 64 + fc * 16 + m15;                                    \
            bfv[fc] = *(const bf16x8*)&b_[row * 32 + ((quad ^ ((row >> 1) & 3)) * 8)]; \
        }                                                                         \
        _Pragma("unroll")                                                         \
        for (int fr = 0; fr < 4; fr++)                                            \
            _Pragma("unroll")                                                     \
            for (int fc = 0; fc < 4; fc++)                                        \
                acc[fr][fc] = __builtin_amdgcn_mfma_f32_16x16x32_bf16(            \
                    af[fr], bfv[fc], acc[fr][fc], 0, 0, 0);                       \
    } while (0)

    STAGE(0, 0);
    STAGE(1, 32);

    int cur = 0;
    #pragma unroll 3
    for (int t = 0; t < 30; ++t) {
        int sb = cur + 2; if (sb >= 3) sb -= 3;
        STAGE(sb, (t + 2) * 32);
        asm volatile("s_waitcnt vmcnt(8)" ::: "memory");
        __builtin_amdgcn_s_barrier();
        COMPUTE(cur);
        __builtin_amdgcn_s_barrier();
        cur = (cur == 2) ? 0 : cur + 1;
    }
    asm volatile("s_waitcnt vmcnt(4)" ::: "memory");
    __builtin_amdgcn_s_barrier();
    COMPUTE(cur);
    cur = (cur == 2) ? 0 : cur + 1;
    asm volatile("s_waitcnt vmcnt(0)" ::: "memory");
    __builtin_amdgcn_s_barrier();
    COMPUTE(cur);

#undef STAGE
#undef COMPUTE

    const float* bias = (z == 0) ? bk : (z == 1) ? bq : bv;
    ushort* dstA = (z == 0) ? kd : qd;
    for (int fr = 0; fr < 4; fr++) {
        int ibase = row0 + wr * 64 + fr * 16 + quad * 4;
        int b_ = ibase >> 10, s = ibase & 1023;
        for (int fc = 0; fc < 4; fc++) {
            int j = col0 + wc * 64 + fc * 16 + m15;
            int h = j >> 6, dh = j & 63;
            float bb = bias[j];
            if (z < 2) {
                for (int r = 0; r < 4; r++)
                    dstA[((b_ * 16 + h) * 1024 + (s + r)) * 64 + dh] = f2bf(acc[fr][fc][r] + bb);
            } else {
                ushort4 o;
                o.x = f2bf(acc[fr][fc][0] + bb);
                o.y = f2bf(acc[fr][fc][1] + bb);
                o.z = f2bf(acc[fr][fc][2] + bb);
                o.w = f2bf(acc[fr][fc][3] + bb);
                *(ushort4*)&vd[((b_ * 16 + h) * 64 + dh) * 1024 + s] = o;
            }
        }
    }
}

// ------- fused mask: lm rows (8 per block) in LDS, then gather -> bf16 -------
__global__ __launch_bounds__(256) void mask_fused(
    const float* __restrict__ m1, const float* __restrict__ m2,
    const int* __restrict__ rb, ushort* __restrict__ gth)
{
    __shared__ float As8[64 * 8];     // m1[m][r][s0..s0+7]    2 KB
    __shared__ float lmS[8 * 1024];   // lm rows               32 KB
    const int s0 = blockIdx.x * 8;
    const int m = blockIdx.y;
    const int tid = threadIdx.x;

    if (tid < 128) {
        int r = tid >> 1, half = tid & 1;
        *(float4*)&As8[r * 8 + half * 4] =
            *(const float4*)&m1[(m * 64 + r) * 1024 + s0 + half * 4];
    }
    __syncthreads();

    f32x4 acc8[8];
    #pragma unroll
    for (int s = 0; s < 8; s++) acc8[s] = (f32x4){0.f, 0.f, 0.f, 0.f};
    const float* m2b = m2 + m * 65536 + tid * 4;
    #pragma unroll 4
    for (int r = 0; r < 64; r++) {
        float4 b4 = *(const float4*)&m2b[r * 1024];
        f32x4 b = (f32x4){b4.x, b4.y, b4.z, b4.w};
        #pragma unroll
        for (int s = 0; s < 8; s++) {
            float a = As8[r * 8 + s];
            acc8[s] += a * b;
        }
    }
    #pragma unroll
    for (int s = 0; s < 8; s++)
        *(f32x4*)&lmS[s * 1024 + tid * 4] = acc8[s];
    __syncthreads();

    const int base = (m * 1024 + s0) * 1024;
    #pragma unroll
    for (int i = 0; i < 8; i++) {
        int c = tid + i * 256;             // 2048 int4 chunks
        int row = c >> 8, j = (c & 255) * 4;
        int4 idx = *(const int4*)&rb[base + row * 1024 + j];
        ushort4 o;
        o.x = f2bf(lmS[row * 1024 + (idx.x & 1023)] * 0.125f);
        o.y = f2bf(lmS[row * 1024 + (idx.y & 1023)] * 0.125f);
        o.z = f2bf(lmS[row * 1024 + (idx.z & 1023)] * 0.125f);
        o.w = f2bf(lmS[row * 1024 + (idx.w & 1023)] * 0.125f);
        *(ushort4*)&gth[base + row * 1024 + j] = o;
    }
}

// ---------------- fused attention: O_unnorm = (QK^T*mask) @ V ; ss = sum P^2 ----------------
// q,k: [B,H,S,64] bf16 ; v: [B,H,64,S] bf16 ; gth: [4,S,S] bf16 (scale folded in)
// Swapped QK^T (mfma(K,Q)); P in-register via permlane32_swap; mask in LDS at
// stride 76; K/V 2-tile reg-prefetch (T14); 2 barriers/iter; T5 setprio.
// T1 XCD swizzle (1024 blocks % 8 == 0, bijective): each XCD owns 8 complete
// bh heads (K/V/Q panels fetched once per XCD instead of 8x duplication —
// measured FETCH_SIZE was ~77 MB vs ~33 MB ideal).
__global__ __launch_bounds__(256, 4) void attention(
    const ushort* __restrict__ qd, const ushort* __restrict__ kd, const ushort* __restrict__ vd,
    const ushort* __restrict__ gth, float* __restrict__ O, float* __restrict__ ss)
{
    __shared__ __align__(16) char ldsraw[28176];
    ushort* Ks  = (ushort*)ldsraw;             // [64][72]  9216 B
    ushort* Vs  = (ushort*)(ldsraw + 9216);    // [64][72]  9216 B
    ushort* Ms  = (ushort*)(ldsraw + 18432);   // [64][76]  9728 B
    float*  red = (float*)(ldsraw + 28160);    // [4]
    float*  fbuf = (float*)ldsraw;             // epilogue overlay [64][66] f32 (16896 B)

    const int bb = blockIdx.x + 16 * blockIdx.y;
    const int lb = (bb & 7) * 128 + (bb >> 3);       // XCD-contiguous remap
    const int s0 = (lb & 15) * 64;
    const int bh = lb >> 4;
    const int mm = bh & 3;
    const int tid = threadIdx.x, lane = tid & 63, wave = tid >> 6;
    const int l31 = lane & 31, hl = lane >> 5;
    const int wr2 = wave >> 1, wc2 = wave & 1;

    // per-thread staging coordinates: chunks c = tid, tid+256
    const int r0_ = tid >> 3,          o0_ = (tid & 7) * 8;
    const int r1_ = (tid + 256) >> 3,  o1_ = ((tid + 256) & 7) * 8;

    const ushort* kdb = kd + bh * 65536;        // [1024][64]
    const ushort* vdb = vd + bh * 65536;        // [64][1024]
    const ushort* gbase = gth + mm * 1048576 + s0 * 1024;   // [64 s][1024 t]

    const int srow = wr2 * 32 + l31;            // this lane's P row (s-local)
    const int tb   = wc2 * 32 + 4 * hl;         // t base within tile

    // ---- prologue: Q through Ks; tile-0 K/V/M into registers ----
    *(uint4*)&Ks[r0_ * 72 + o0_] = *(const uint4*)&qd[(bh * 1024 + s0 + r0_) * 64 + o0_];
    *(uint4*)&Ks[r1_ * 72 + o1_] = *(const uint4*)&qd[(bh * 1024 + s0 + r1_) * 64 + o1_];
    uint4 kr0 = *(const uint4*)&kdb[r0_ * 64 + o0_];
    uint4 kr1 = *(const uint4*)&kdb[r1_ * 64 + o1_];
    uint4 vr0 = *(const uint4*)&vdb[r0_ * 1024 + o0_];
    uint4 vr1 = *(const uint4*)&vdb[r1_ * 1024 + o1_];
    uint4 mr0 = *(const uint4*)&gbase[r0_ * 1024 + o0_];
    uint4 mr1 = *(const uint4*)&gbase[r1_ * 1024 + o1_];
    __syncthreads();
    bf16x8 qf[4];
    #pragma unroll
    for (int kk = 0; kk < 4; kk++)
        qf[kk] = *(const bf16x8*)&Ks[srow * 72 + kk * 16 + hl * 8];
    __syncthreads();   // qf reads done; Ks free for K tiles

    // write tile-0 regs -> LDS (M split into 2x uint2 at stride 76), issue tile-1
    *(uint4*)&Ks[r0_ * 72 + o0_] = kr0;
    *(uint4*)&Ks[r1_ * 72 + o1_] = kr1;
    *(uint4*)&Vs[r0_ * 72 + o0_] = vr0;
    *(uint4*)&Vs[r1_ * 72 + o1_] = vr1;
    *(uint2*)&Ms[r0_ * 76 + o0_]     = make_uint2(mr0.x, mr0.y);
    *(uint2*)&Ms[r0_ * 76 + o0_ + 4] = make_uint2(mr0.z, mr0.w);
    *(uint2*)&Ms[r1_ * 76 + o1_]     = make_uint2(mr1.x, mr1.y);
    *(uint2*)&Ms[r1_ * 76 + o1_ + 4] = make_uint2(mr1.z, mr1.w);
    kr0 = *(const uint4*)&kdb[(64 + r0_) * 64 + o0_];
    kr1 = *(const uint4*)&kdb[(64 + r1_) * 64 + o1_];
    vr0 = *(const uint4*)&vdb[r0_ * 1024 + 64 + o0_];
    vr1 = *(const uint4*)&vdb[r1_ * 1024 + 64 + o1_];
    mr0 = *(const uint4*)&gbase[r0_ * 1024 + 64 + o0_];
    mr1 = *(const uint4*)&gbase[r1_ * 1024 + 64 + o1_];
    __syncthreads();   // tile 0 visible

    f32x16 oaccA, oaccB;
    #pragma unroll
    for (int i = 0; i < 16; i++) { oaccA[i] = 0.f; oaccB[i] = 0.f; }
    float ss0 = 0.f, ss1 = 0.f, ss2 = 0.f, ss3 = 0.f;

    for (int t = 0; t < 16; ++t) {
        // QK^T swapped: A = K rows (t on regs), B = Q rows (s on lanes)
        f32x16 p;
        #pragma unroll
        for (int i = 0; i < 16; i++) p[i] = 0.f;
        __builtin_amdgcn_s_setprio(1);
        #pragma unroll
        for (int kk = 0; kk < 4; kk++) {
            bf16x8 kf = *(const bf16x8*)&Ks[(wc2 * 32 + l31) * 72 + kk * 16 + hl * 8];
            p = __builtin_amdgcn_mfma_f32_32x32x16_bf16(kf, qf[kk], p, 0, 0, 0);
        }
        __builtin_amdgcn_s_setprio(0);
        // mask-multiply (vector LDS reads), square-sum, pack to bf16 pairs.
        // p[4g+e] = P[s=srow][t_loc = tb + 8g + e], tb = wc2*32 + 4*hl
        unsigned u[8];
        #pragma unroll
        for (int g = 0; g < 4; g++) {
            ushort4 mk = *(const ushort4*)&Ms[srow * 76 + tb + 8 * g];
            float pv0 = p[4 * g + 0] * bf2f(mk.x);
            float pv1 = p[4 * g + 1] * bf2f(mk.y);
            float pv2 = p[4 * g + 2] * bf2f(mk.z);
            float pv3 = p[4 * g + 3] * bf2f(mk.w);
            ss0 += pv0 * pv0; ss1 += pv1 * pv1;
            ss2 += pv2 * pv2; ss3 += pv3 * pv3;
            u[2 * g]     = packbf(pv0, pv1);
            u[2 * g + 1] = packbf(pv2, pv3);
        }
        // lane-pair (l31, hl=0/1) t-quad exchange: one swap fills two frag slots.
        auto r02 = __builtin_amdgcn_permlane32_swap(u[0], u[2], false, false);
        auto r13 = __builtin_amdgcn_permlane32_swap(u[1], u[3], false, false);
        auto r46 = __builtin_amdgcn_permlane32_swap(u[4], u[6], false, false);
        auto r57 = __builtin_amdgcn_permlane32_swap(u[5], u[7], false, false);
        union { unsigned q[4]; bf16x8 v; } af0, af1;
        af0.q[0] = r02[0]; af0.q[1] = r13[0]; af0.q[2] = r02[1]; af0.q[3] = r13[1];
        af1.q[0] = r46[0]; af1.q[1] = r57[0]; af1.q[2] = r46[1]; af1.q[3] = r57[1];
        // PV over this wave's t-half: partial O for all 64 dh (2 halves)
        __builtin_amdgcn_s_setprio(1);
        {
            const ushort* vrA = &Vs[l31 * 72 + wc2 * 32];
            bf16x8 b00 = *(const bf16x8*)&vrA[hl * 8];
            bf16x8 b01 = *(const bf16x8*)&vrA[16 + hl * 8];
            oaccA = __builtin_amdgcn_mfma_f32_32x32x16_bf16(af0.v, b00, oaccA, 0, 0, 0);
            oaccA = __builtin_amdgcn_mfma_f32_32x32x16_bf16(af1.v, b01, oaccA, 0, 0, 0);
            const ushort* vrB = &Vs[(32 + l31) * 72 + wc2 * 32];
            bf16x8 b10 = *(const bf16x8*)&vrB[hl * 8];
            bf16x8 b11 = *(const bf16x8*)&vrB[16 + hl * 8];
            oaccB = __builtin_amdgcn_mfma_f32_32x32x16_bf16(af0.v, b10, oaccB, 0, 0, 0);
            oaccB = __builtin_amdgcn_mfma_f32_32x32x16_bf16(af1.v, b11, oaccB, 0, 0, 0);
        }
        __builtin_amdgcn_s_setprio(0);
        __syncthreads();   // all LDS reads of tile t done; safe to overwrite
        if (t < 15) {
            *(uint4*)&Ks[r0_ * 72 + o0_] = kr0;
            *(uint4*)&Ks[r1_ * 72 + o1_] = kr1;
            *(uint4*)&Vs[r0_ * 72 + o0_] = vr0;
            *(uint4*)&Vs[r1_ * 72 + o1_] = vr1;
            *(uint2*)&Ms[r0_ * 76 + o0_]     = make_uint2(mr0.x, mr0.y);
            *(uint2*)&Ms[r0_ * 76 + o0_ + 4] = make_uint2(mr0.z, mr0.w);
            *(uint2*)&Ms[r1_ * 76 + o1_]     = make_uint2(mr1.x, mr1.y);
            *(uint2*)&Ms[r1_ * 76 + o1_ + 4] = make_uint2(mr1.z, mr1.w);
            if (t < 14) {
                const int tn = (t + 2) * 64;
                kr0 = *(const uint4*)&kdb[(tn + r0_) * 64 + o0_];
                kr1 = *(const uint4*)&kdb[(tn + r1_) * 64 + o1_];
                vr0 = *(const uint4*)&vdb[r0_ * 1024 + tn + o0_];
                vr1 = *(const uint4*)&vdb[r1_ * 1024 + tn + o1_];
                mr0 = *(const uint4*)&gbase[r0_ * 1024 + tn + o0_];
                mr1 = *(const uint4*)&gbase[r1_ * 1024 + tn + o1_];
            }
            __syncthreads();   // tile t+1 visible
        }
    }

    // ---- epilogue: merge partial O across the wc2 wave pair (once per block) ----
    if (wc2 == 1) {
        #pragma unroll
        for (int reg = 0; reg < 16; reg++) {
            int row = wr2 * 32 + (reg & 3) + 8 * (reg >> 2) + 4 * hl;
            fbuf[row * 66 + l31]      = oaccA[reg];
            fbuf[row * 66 + 32 + l31] = oaccB[reg];
        }
    }
    __syncthreads();
    if (wc2 == 0) {
        #pragma unroll
        for (int reg = 0; reg < 16; reg++) {
            int rl = (reg & 3) + 8 * (reg >> 2) + 4 * hl;
            int s = s0 + wr2 * 32 + rl;
            float a = oaccA[reg] + fbuf[(wr2 * 32 + rl) * 66 + l31];
            float b = oaccB[reg] + fbuf[(wr2 * 32 + rl) * 66 + 32 + l31];
            O[(bh * 1024 + s) * 64 + l31]      = a;
            O[(bh * 1024 + s) * 64 + 32 + l31] = b;
        }
    }
    float ssacc = (ss0 + ss1) + (ss2 + ss3);
    for (int off = 32; off; off >>= 1) ssacc += __shfl_down(ssacc, off, 64);
    if (lane == 0) red[wave] = ssacc;
    __syncthreads();
    if (tid == 0) atomicAdd(&ss[bh], red[0] + red[1] + red[2] + red[3]);
}

// ---------------- normalize + transpose to [B,S,H,DH] ----------------
__global__ __launch_bounds__(256) void normalize_out(const float* __restrict__ O,
                                                     const float* __restrict__ ss,
                                                     float* __restrict__ out)
{
    int gid = blockIdx.x * 256 + threadIdx.x;
    int e = gid * 4;
    int bh = e >> 16;
    float inv = 1.f / (sqrtf(ss[bh]) + 1e-8f);
    float4 v4 = *(const float4*)&O[e];
    int b_ = bh >> 4, h = bh & 15;
    int s = (e >> 6) & 1023, dh = e & 63;
    float4 o4 = {v4.x * inv, v4.y * inv, v4.z * inv, v4.w * inv};
    *(float4*)&out[((b_ * 1024 + s) * 16 + h) * 64 + dh] = o4;
}

extern "C" void kernel_launch(void* const* d_in, const int* in_sizes, int n_in,
                              void* d_out, int out_size, void* d_ws, size_t ws_size,
                              hipStream_t stream) {
    const float* x  = (const float*)d_in[0];
    const float* Wk = (const float*)d_in[1];
    const float* bk = (const float*)d_in[2];
    const float* Wq = (const float*)d_in[3];
    const float* bq = (const float*)d_in[4];
    const float* Wv = (const float*)d_in[5];
    const float* bv = (const float*)d_in[6];
    const float* m1 = (const float*)d_in[7];
    const float* m2 = (const float*)d_in[8];
    const int*   rb = (const int*)d_in[9];
    float* out = (float*)d_out;

    char* ws = (char*)d_ws;
    ushort* xb    = (ushort*)(ws);                  //  8 MB  [4096,1024] bf16
    ushort* wball = (ushort*)(ws + 8388608);        //  6 MB  3x[1024,1024] bf16
    ushort* kd    = (ushort*)(ws + 14680064);       //  8 MB  [B,H,S,DH] bf16
    ushort* qd    = (ushort*)(ws + 23068672);       //  8 MB
    ushort* vd    = (ushort*)(ws + 31457280);       //  8 MB  [B,H,DH,S] bf16
    float*  O     = (float*)(ws + 39845888);        // 16 MB  [B,H,S,DH] f32
    ushort* gth   = (ushort*)(ws + 56623104);       //  8 MB  [M,S,S] bf16
    float*  ssb   = (float*)(ws + 65011712);        // 64 f32

    convert_all<<<7168, 256, 0, stream>>>(x, Wk, Wq, Wv, xb, wball);
    proj_gemm<<<dim3(32, 8, 3), 256, 0, stream>>>(xb, wball, bk, bq, bv, kd, qd, vd);
    mask_fused<<<dim3(128, 4), 256, 0, stream>>>(m1, m2, rb, gth);
    hipMemsetAsync(ssb, 0, 64 * sizeof(float), stream);
    attention<<<dim3(16, 64), 256, 0, stream>>>(qd, kd, vd, gth, O, ssb);
    normalize_out<<<4096, 256, 0, stream>>>(O, ssb, out);
}

// Round 7
// 187.094 us; speedup vs baseline: 1.0285x; 1.0285x over previous
//
#include <hip/hip_runtime.h>
#include <hip/hip_bf16.h>
#include <stdint.h>

typedef __attribute__((ext_vector_type(8))) __bf16 bf16x8;
typedef __attribute__((ext_vector_type(4))) float  f32x4;
typedef __attribute__((ext_vector_type(16))) float f32x16;

__device__ __forceinline__ ushort f2bf(float f) {
    union { float f; uint32_t u; } v; v.f = f;
    uint32_t u = v.u;
    uint32_t r = 0x7FFFu + ((u >> 16) & 1u);
    return (ushort)((u + r) >> 16);
}
__device__ __forceinline__ float bf2f(ushort u) {
    union { uint32_t u; float f; } v; v.u = ((uint32_t)u) << 16;
    return v.f;
}
// packed RNE f32->bf16 pair (T12 recipe; no builtin on gfx950). Same rounding
// as f2bf (RNE) -> bit-identical results, 1 instr instead of ~12 VALU ops.
__device__ __forceinline__ unsigned cvtpk(float lo, float hi) {
    unsigned r;
    asm("v_cvt_pk_bf16_f32 %0, %1, %2" : "=v"(r) : "v"(lo), "v"(hi));
    return r;
}

// async global->LDS, 16B per lane; LDS dest must be wave-uniform base + lane*16
typedef __attribute__((address_space(3))) uint32_t lds_u32_t;
typedef const __attribute__((address_space(1))) uint32_t glb_u32_t;
__device__ __forceinline__ void async_copy16(const void* g, void* l) {
    __builtin_amdgcn_global_load_lds((glb_u32_t*)g, (lds_u32_t*)l, 16, 0, 0);
}

// ------------- merged convert fp32 -> bf16: x then Wk,Wq,Wv -------------
__global__ __launch_bounds__(256) void convert_all(
    const float* __restrict__ x, const float* __restrict__ wk,
    const float* __restrict__ wq, const float* __restrict__ wv,
    ushort* __restrict__ xb, ushort* __restrict__ wball)
{
    int i = blockIdx.x * 256 + threadIdx.x;   // 1835008 float4 chunks total
    const float* src; ushort* dst; int j;
    if (i < 1048576) { src = x; dst = xb; j = i; }
    else {
        int t = i - 1048576;
        int z = t >> 18;             // 0..2
        j = t & 262143;
        src = (z == 0) ? wk : (z == 1) ? wq : wv;
        dst = wball + z * 1048576;
    }
    float4 f = ((const float4*)src)[j];
    ushort4 o;
    o.x = f2bf(f.x); o.y = f2bf(f.y); o.z = f2bf(f.z); o.w = f2bf(f.w);
    ((ushort4*)dst)[j] = o;
}

// ---------------- QKV projection GEMM: Y = X @ W^T + b ----------------
// 2-deep pipelined: BK=32, 3-deep LDS ring, raw s_barrier + counted
// s_waitcnt vmcnt(8) so 2 tiles of global_load_lds stay in flight.
// NOTE (R6 lesson): no XCD swizzle — all 768 blocks are co-resident (3/CU),
// so dispatch-order locality doesn't apply and the remap regressed ~2-4 us.
__global__ __launch_bounds__(256) void proj_gemm(
    const ushort* __restrict__ xb, const ushort* __restrict__ wball,
    const float* __restrict__ bk, const float* __restrict__ bq, const float* __restrict__ bv,
    ushort* __restrict__ kd, ushort* __restrict__ qd, ushort* __restrict__ vd)
{
    __shared__ ushort As[3 * 128 * 32];   // 24 KB, 3-deep ring
    __shared__ ushort Bs[3 * 128 * 32];   // 24 KB
    const int z = blockIdx.z;
    const int row0 = blockIdx.x * 128;
    const int col0 = blockIdx.y * 128;
    const ushort* wb = wball + z * 1048576;
    const int tid = threadIdx.x;
    const int lane = tid & 63, wave = tid >> 6;
    const int quad = lane >> 4, m15 = lane & 15;
    const int wr = wave >> 1, wc = wave & 1;

    f32x4 acc[4][4];
    for (int i = 0; i < 4; i++)
        for (int j = 0; j < 4; j++) acc[i][j] = (f32x4){0.f, 0.f, 0.f, 0.f};

#define STAGE(BI, KK) do {                                                        \
        _Pragma("unroll")                                                         \
        for (int i_ = 0; i_ < 2; i_++) {                                          \
            int c_ = tid + i_ * 256;           /* 0..511 */                       \
            int r_ = c_ >> 2, cjp_ = c_ & 3;                                      \
            int cj_ = cjp_ ^ ((r_ >> 1) & 3);                                     \
            async_copy16(&xb[(row0 + r_) * 1024 + (KK) + cj_ * 8],                \
                         &As[(BI) * 4096 + c_ * 8]);                              \
            async_copy16(&wb[(col0 + r_) * 1024 + (KK) + cj_ * 8],                \
                         &Bs[(BI) * 4096 + c_ * 8]);                              \
        }                                                                         \
    } while (0)

#define COMPUTE(BI) do {                                                          \
        const ushort* a_ = &As[(BI) * 4096];                                      \
        const ushort* b_ = &Bs[(BI) * 4096];                                      \
        bf16x8 af[4], bfv[4];                                                     \
        _Pragma("unroll")                                                         \
        for (int fr = 0; fr < 4; fr++) {                                          \
            int row = wr * 64 + fr * 16 + m15;                                    \
            af[fr] = *(const bf16x8*)&a_[row * 32 + ((quad ^ ((row >> 1) & 3)) * 8)]; \
        }                                                                         \
        _Pragma("unroll")                                                         \
        for (int fc = 0; fc < 4; fc++) {                                          \
            int row = wc * 64 + fc * 16 + m15;                                    \
            bfv[fc] = *(const bf16x8*)&b_[row * 32 + ((quad ^ ((row >> 1) & 3)) * 8)]; \
        }                                                                         \
        _Pragma("unroll")                                                         \
        for (int fr = 0; fr < 4; fr++)                                            \
            _Pragma("unroll")                                                     \
            for (int fc = 0; fc < 4; fc++)                                        \
                acc[fr][fc] = __builtin_amdgcn_mfma_f32_16x16x32_bf16(            \
                    af[fr], bfv[fc], acc[fr][fc], 0, 0, 0);                       \
    } while (0)

    STAGE(0, 0);
    STAGE(1, 32);

    int cur = 0;
    #pragma unroll 3
    for (int t = 0; t < 30; ++t) {
        int sb = cur + 2; if (sb >= 3) sb -= 3;
        STAGE(sb, (t + 2) * 32);
        asm volatile("s_waitcnt vmcnt(8)" ::: "memory");
        __builtin_amdgcn_s_barrier();
        COMPUTE(cur);
        __builtin_amdgcn_s_barrier();
        cur = (cur == 2) ? 0 : cur + 1;
    }
    asm volatile("s_waitcnt vmcnt(4)" ::: "memory");
    __builtin_amdgcn_s_barrier();
    COMPUTE(cur);
    cur = (cur == 2) ? 0 : cur + 1;
    asm volatile("s_waitcnt vmcnt(0)" ::: "memory");
    __builtin_amdgcn_s_barrier();
    COMPUTE(cur);

#undef STAGE
#undef COMPUTE

    const float* bias = (z == 0) ? bk : (z == 1) ? bq : bv;
    ushort* dstA = (z == 0) ? kd : qd;
    for (int fr = 0; fr < 4; fr++) {
        int ibase = row0 + wr * 64 + fr * 16 + quad * 4;
        int b_ = ibase >> 10, s = ibase & 1023;
        for (int fc = 0; fc < 4; fc++) {
            int j = col0 + wc * 64 + fc * 16 + m15;
            int h = j >> 6, dh = j & 63;
            float bb = bias[j];
            if (z < 2) {
                for (int r = 0; r < 4; r++)
                    dstA[((b_ * 16 + h) * 1024 + (s + r)) * 64 + dh] = f2bf(acc[fr][fc][r] + bb);
            } else {
                ushort4 o;
                o.x = f2bf(acc[fr][fc][0] + bb);
                o.y = f2bf(acc[fr][fc][1] + bb);
                o.z = f2bf(acc[fr][fc][2] + bb);
                o.w = f2bf(acc[fr][fc][3] + bb);
                *(ushort4*)&vd[((b_ * 16 + h) * 64 + dh) * 1024 + s] = o;
            }
        }
    }
}

// ------- fused mask: lm rows (8 per block) in LDS, then gather -> bf16 -------
__global__ __launch_bounds__(256) void mask_fused(
    const float* __restrict__ m1, const float* __restrict__ m2,
    const int* __restrict__ rb, ushort* __restrict__ gth)
{
    __shared__ float As8[64 * 8];     // m1[m][r][s0..s0+7]    2 KB
    __shared__ float lmS[8 * 1024];   // lm rows               32 KB
    const int s0 = blockIdx.x * 8;
    const int m = blockIdx.y;
    const int tid = threadIdx.x;

    if (tid < 128) {
        int r = tid >> 1, half = tid & 1;
        *(float4*)&As8[r * 8 + half * 4] =
            *(const float4*)&m1[(m * 64 + r) * 1024 + s0 + half * 4];
    }
    __syncthreads();

    f32x4 acc8[8];
    #pragma unroll
    for (int s = 0; s < 8; s++) acc8[s] = (f32x4){0.f, 0.f, 0.f, 0.f};
    const float* m2b = m2 + m * 65536 + tid * 4;
    #pragma unroll 4
    for (int r = 0; r < 64; r++) {
        float4 b4 = *(const float4*)&m2b[r * 1024];
        f32x4 b = (f32x4){b4.x, b4.y, b4.z, b4.w};
        #pragma unroll
        for (int s = 0; s < 8; s++) {
            float a = As8[r * 8 + s];
            acc8[s] += a * b;
        }
    }
    #pragma unroll
    for (int s = 0; s < 8; s++)
        *(f32x4*)&lmS[s * 1024 + tid * 4] = acc8[s];
    __syncthreads();

    const int base = (m * 1024 + s0) * 1024;
    #pragma unroll
    for (int i = 0; i < 8; i++) {
        int c = tid + i * 256;             // 2048 int4 chunks
        int row = c >> 8, j = (c & 255) * 4;
        int4 idx = *(const int4*)&rb[base + row * 1024 + j];
        ushort4 o;
        o.x = f2bf(lmS[row * 1024 + (idx.x & 1023)] * 0.125f);
        o.y = f2bf(lmS[row * 1024 + (idx.y & 1023)] * 0.125f);
        o.z = f2bf(lmS[row * 1024 + (idx.z & 1023)] * 0.125f);
        o.w = f2bf(lmS[row * 1024 + (idx.w & 1023)] * 0.125f);
        *(ushort4*)&gth[base + row * 1024 + j] = o;
    }
}

// ---------------- fused attention: O_unnorm = (QK^T*mask) @ V ; ss = sum P^2 ----------------
// q,k: [B,H,S,64] bf16 ; v: [B,H,64,S] bf16 ; gth: [4,S,S] bf16 (scale folded in)
// Swapped QK^T (mfma(K,Q)): p lane = s-row (l31), regs = t (4 consecutive per quad).
// P never touches LDS: in-register mask-multiply -> v_cvt_pk_bf16_f32 pack (1 instr
// per bf16 pair; RNE, bit-identical to f2bf) -> 4x permlane32_swap to assemble PV
// A-fragments. Partial O merged across the wc2 wave pair once per block via an
// LDS f32 overlay. 2 barriers/iter; T5 setprio; mask in LDS at stride 76
// (conflict-free b64); K/V 2-tile reg-prefetch (T14). No XCD swizzle (R6 lesson:
// all 1024 blocks co-resident at 4/CU -> remap regressed).
__global__ __launch_bounds__(256, 4) void attention(
    const ushort* __restrict__ qd, const ushort* __restrict__ kd, const ushort* __restrict__ vd,
    const ushort* __restrict__ gth, float* __restrict__ O, float* __restrict__ ss)
{
    __shared__ __align__(16) char ldsraw[28176];
    ushort* Ks  = (ushort*)ldsraw;             // [64][72]  9216 B
    ushort* Vs  = (ushort*)(ldsraw + 9216);    // [64][72]  9216 B
    ushort* Ms  = (ushort*)(ldsraw + 18432);   // [64][76]  9728 B
    float*  red = (float*)(ldsraw + 28160);    // [4]
    float*  fbuf = (float*)ldsraw;             // epilogue overlay [64][66] f32 (16896 B)

    const int s0 = blockIdx.x * 64;
    const int bh = blockIdx.y;
    const int mm = bh & 3;
    const int tid = threadIdx.x, lane = tid & 63, wave = tid >> 6;
    const int l31 = lane & 31, hl = lane >> 5;
    const int wr2 = wave >> 1, wc2 = wave & 1;

    // per-thread staging coordinates: chunks c = tid, tid+256
    const int r0_ = tid >> 3,          o0_ = (tid & 7) * 8;
    const int r1_ = (tid + 256) >> 3,  o1_ = ((tid + 256) & 7) * 8;

    const ushort* kdb = kd + bh * 65536;        // [1024][64]
    const ushort* vdb = vd + bh * 65536;        // [64][1024]
    const ushort* gbase = gth + mm * 1048576 + s0 * 1024;   // [64 s][1024 t]

    const int srow = wr2 * 32 + l31;            // this lane's P row (s-local)
    const int tb   = wc2 * 32 + 4 * hl;         // t base within tile

    // ---- prologue: Q through Ks; tile-0 K/V/M into registers ----
    *(uint4*)&Ks[r0_ * 72 + o0_] = *(const uint4*)&qd[(bh * 1024 + s0 + r0_) * 64 + o0_];
    *(uint4*)&Ks[r1_ * 72 + o1_] = *(const uint4*)&qd[(bh * 1024 + s0 + r1_) * 64 + o1_];
    uint4 kr0 = *(const uint4*)&kdb[r0_ * 64 + o0_];
    uint4 kr1 = *(const uint4*)&kdb[r1_ * 64 + o1_];
    uint4 vr0 = *(const uint4*)&vdb[r0_ * 1024 + o0_];
    uint4 vr1 = *(const uint4*)&vdb[r1_ * 1024 + o1_];
    uint4 mr0 = *(const uint4*)&gbase[r0_ * 1024 + o0_];
    uint4 mr1 = *(const uint4*)&gbase[r1_ * 1024 + o1_];
    __syncthreads();
    bf16x8 qf[4];
    #pragma unroll
    for (int kk = 0; kk < 4; kk++)
        qf[kk] = *(const bf16x8*)&Ks[srow * 72 + kk * 16 + hl * 8];
    __syncthreads();   // qf reads done; Ks free for K tiles

    // write tile-0 regs -> LDS (M split into 2x uint2 at stride 76), issue tile-1
    *(uint4*)&Ks[r0_ * 72 + o0_] = kr0;
    *(uint4*)&Ks[r1_ * 72 + o1_] = kr1;
    *(uint4*)&Vs[r0_ * 72 + o0_] = vr0;
    *(uint4*)&Vs[r1_ * 72 + o1_] = vr1;
    *(uint2*)&Ms[r0_ * 76 + o0_]     = make_uint2(mr0.x, mr0.y);
    *(uint2*)&Ms[r0_ * 76 + o0_ + 4] = make_uint2(mr0.z, mr0.w);
    *(uint2*)&Ms[r1_ * 76 + o1_]     = make_uint2(mr1.x, mr1.y);
    *(uint2*)&Ms[r1_ * 76 + o1_ + 4] = make_uint2(mr1.z, mr1.w);
    kr0 = *(const uint4*)&kdb[(64 + r0_) * 64 + o0_];
    kr1 = *(const uint4*)&kdb[(64 + r1_) * 64 + o1_];
    vr0 = *(const uint4*)&vdb[r0_ * 1024 + 64 + o0_];
    vr1 = *(const uint4*)&vdb[r1_ * 1024 + 64 + o1_];
    mr0 = *(const uint4*)&gbase[r0_ * 1024 + 64 + o0_];
    mr1 = *(const uint4*)&gbase[r1_ * 1024 + 64 + o1_];
    __syncthreads();   // tile 0 visible

    f32x16 oaccA, oaccB;
    #pragma unroll
    for (int i = 0; i < 16; i++) { oaccA[i] = 0.f; oaccB[i] = 0.f; }
    float ss0 = 0.f, ss1 = 0.f, ss2 = 0.f, ss3 = 0.f;

    for (int t = 0; t < 16; ++t) {
        // QK^T swapped: A = K rows (t on regs), B = Q rows (s on lanes)
        f32x16 p;
        #pragma unroll
        for (int i = 0; i < 16; i++) p[i] = 0.f;
        __builtin_amdgcn_s_setprio(1);
        #pragma unroll
        for (int kk = 0; kk < 4; kk++) {
            bf16x8 kf = *(const bf16x8*)&Ks[(wc2 * 32 + l31) * 72 + kk * 16 + hl * 8];
            p = __builtin_amdgcn_mfma_f32_32x32x16_bf16(kf, qf[kk], p, 0, 0, 0);
        }
        __builtin_amdgcn_s_setprio(0);
        // mask-multiply (vector LDS reads), square-sum, cvt_pk pack to bf16 pairs.
        // p[4g+e] = P[s=srow][t_loc = tb + 8g + e], tb = wc2*32 + 4*hl
        unsigned u[8];
        #pragma unroll
        for (int g = 0; g < 4; g++) {
            ushort4 mk = *(const ushort4*)&Ms[srow * 76 + tb + 8 * g];
            float pv0 = p[4 * g + 0] * bf2f(mk.x);
            float pv1 = p[4 * g + 1] * bf2f(mk.y);
            float pv2 = p[4 * g + 2] * bf2f(mk.z);
            float pv3 = p[4 * g + 3] * bf2f(mk.w);
            ss0 += pv0 * pv0; ss1 += pv1 * pv1;
            ss2 += pv2 * pv2; ss3 += pv3 * pv3;
            u[2 * g]     = cvtpk(pv0, pv1);
            u[2 * g + 1] = cvtpk(pv2, pv3);
        }
        // lane-pair (l31, hl=0/1) t-quad exchange: one swap fills two frag slots.
        auto r02 = __builtin_amdgcn_permlane32_swap(u[0], u[2], false, false);
        auto r13 = __builtin_amdgcn_permlane32_swap(u[1], u[3], false, false);
        auto r46 = __builtin_amdgcn_permlane32_swap(u[4], u[6], false, false);
        auto r57 = __builtin_amdgcn_permlane32_swap(u[5], u[7], false, false);
        union { unsigned q[4]; bf16x8 v; } af0, af1;
        af0.q[0] = r02[0]; af0.q[1] = r13[0]; af0.q[2] = r02[1]; af0.q[3] = r13[1];
        af1.q[0] = r46[0]; af1.q[1] = r57[0]; af1.q[2] = r46[1]; af1.q[3] = r57[1];
        // PV over this wave's t-half: partial O for all 64 dh (2 halves)
        __builtin_amdgcn_s_setprio(1);
        {
            const ushort* vrA = &Vs[l31 * 72 + wc2 * 32];
            bf16x8 b00 = *(const bf16x8*)&vrA[hl * 8];
            bf16x8 b01 = *(const bf16x8*)&vrA[16 + hl * 8];
            oaccA = __builtin_amdgcn_mfma_f32_32x32x16_bf16(af0.v, b00, oaccA, 0, 0, 0);
            oaccA = __builtin_amdgcn_mfma_f32_32x32x16_bf16(af1.v, b01, oaccA, 0, 0, 0);
            const ushort* vrB = &Vs[(32 + l31) * 72 + wc2 * 32];
            bf16x8 b10 = *(const bf16x8*)&vrB[hl * 8];
            bf16x8 b11 = *(const bf16x8*)&vrB[16 + hl * 8];
            oaccB = __builtin_amdgcn_mfma_f32_32x32x16_bf16(af0.v, b10, oaccB, 0, 0, 0);
            oaccB = __builtin_amdgcn_mfma_f32_32x32x16_bf16(af1.v, b11, oaccB, 0, 0, 0);
        }
        __builtin_amdgcn_s_setprio(0);
        __syncthreads();   // all LDS reads of tile t done; safe to overwrite
        if (t < 15) {
            *(uint4*)&Ks[r0_ * 72 + o0_] = kr0;
            *(uint4*)&Ks[r1_ * 72 + o1_] = kr1;
            *(uint4*)&Vs[r0_ * 72 + o0_] = vr0;
            *(uint4*)&Vs[r1_ * 72 + o1_] = vr1;
            *(uint2*)&Ms[r0_ * 76 + o0_]     = make_uint2(mr0.x, mr0.y);
            *(uint2*)&Ms[r0_ * 76 + o0_ + 4] = make_uint2(mr0.z, mr0.w);
            *(uint2*)&Ms[r1_ * 76 + o1_]     = make_uint2(mr1.x, mr1.y);
            *(uint2*)&Ms[r1_ * 76 + o1_ + 4] = make_uint2(mr1.z, mr1.w);
            if (t < 14) {
                const int tn = (t + 2) * 64;
                kr0 = *(const uint4*)&kdb[(tn + r0_) * 64 + o0_];
                kr1 = *(const uint4*)&kdb[(tn + r1_) * 64 + o1_];
                vr0 = *(const uint4*)&vdb[r0_ * 1024 + tn + o0_];
                vr1 = *(const uint4*)&vdb[r1_ * 1024 + tn + o1_];
                mr0 = *(const uint4*)&gbase[r0_ * 1024 + tn + o0_];
                mr1 = *(const uint4*)&gbase[r1_ * 1024 + tn + o1_];
            }
            __syncthreads();   // tile t+1 visible
        }
    }

    // ---- epilogue: merge partial O across the wc2 wave pair (once per block) ----
    if (wc2 == 1) {
        #pragma unroll
        for (int reg = 0; reg < 16; reg++) {
            int row = wr2 * 32 + (reg & 3) + 8 * (reg >> 2) + 4 * hl;
            fbuf[row * 66 + l31]      = oaccA[reg];
            fbuf[row * 66 + 32 + l31] = oaccB[reg];
        }
    }
    __syncthreads();
    if (wc2 == 0) {
        #pragma unroll
        for (int reg = 0; reg < 16; reg++) {
            int rl = (reg & 3) + 8 * (reg >> 2) + 4 * hl;
            int s = s0 + wr2 * 32 + rl;
            float a = oaccA[reg] + fbuf[(wr2 * 32 + rl) * 66 + l31];
            float b = oaccB[reg] + fbuf[(wr2 * 32 + rl) * 66 + 32 + l31];
            O[(bh * 1024 + s) * 64 + l31]      = a;
            O[(bh * 1024 + s) * 64 + 32 + l31] = b;
        }
    }
    float ssacc = (ss0 + ss1) + (ss2 + ss3);
    for (int off = 32; off; off >>= 1) ssacc += __shfl_down(ssacc, off, 64);
    if (lane == 0) red[wave] = ssacc;
    __syncthreads();
    if (tid == 0) atomicAdd(&ss[bh], red[0] + red[1] + red[2] + red[3]);
}

// ---------------- normalize + transpose to [B,S,H,DH] ----------------
__global__ __launch_bounds__(256) void normalize_out(const float* __restrict__ O,
                                                     const float* __restrict__ ss,
                                                     float* __restrict__ out)
{
    int gid = blockIdx.x * 256 + threadIdx.x;
    int e = gid * 4;
    int bh = e >> 16;
    float inv = 1.f / (sqrtf(ss[bh]) + 1e-8f);
    float4 v4 = *(const float4*)&O[e];
    int b_ = bh >> 4, h = bh & 15;
    int s = (e >> 6) & 1023, dh = e & 63;
    float4 o4 = {v4.x * inv, v4.y * inv, v4.z * inv, v4.w * inv};
    *(float4*)&out[((b_ * 1024 + s) * 16 + h) * 64 + dh] = o4;
}

extern "C" void kernel_launch(void* const* d_in, const int* in_sizes, int n_in,
                              void* d_out, int out_size, void* d_ws, size_t ws_size,
                              hipStream_t stream) {
    const float* x  = (const float*)d_in[0];
    const float* Wk = (const float*)d_in[1];
    const float* bk = (const float*)d_in[2];
    const float* Wq = (const float*)d_in[3];
    const float* bq = (const float*)d_in[4];
    const float* Wv = (const float*)d_in[5];
    const float* bv = (const float*)d_in[6];
    const float* m1 = (const float*)d_in[7];
    const float* m2 = (const float*)d_in[8];
    const int*   rb = (const int*)d_in[9];
    float* out = (float*)d_out;

    char* ws = (char*)d_ws;
    ushort* xb    = (ushort*)(ws);                  //  8 MB  [4096,1024] bf16
    ushort* wball = (ushort*)(ws + 8388608);        //  6 MB  3x[1024,1024] bf16
    ushort* kd    = (ushort*)(ws + 14680064);       //  8 MB  [B,H,S,DH] bf16
    ushort* qd    = (ushort*)(ws + 23068672);       //  8 MB
    ushort* vd    = (ushort*)(ws + 31457280);       //  8 MB  [B,H,DH,S] bf16
    float*  O     = (float*)(ws + 39845888);        // 16 MB  [B,H,S,DH] f32
    ushort* gth   = (ushort*)(ws + 56623104);       //  8 MB  [M,S,S] bf16
    float*  ssb   = (float*)(ws + 65011712);        // 64 f32

    convert_all<<<7168, 256, 0, stream>>>(x, Wk, Wq, Wv, xb, wball);
    proj_gemm<<<dim3(32, 8, 3), 256, 0, stream>>>(xb, wball, bk, bq, bv, kd, qd, vd);
    mask_fused<<<dim3(128, 4), 256, 0, stream>>>(m1, m2, rb, gth);
    hipMemsetAsync(ssb, 0, 64 * sizeof(float), stream);
    attention<<<dim3(16, 64), 256, 0, stream>>>(qd, kd, vd, gth, O, ssb);
    normalize_out<<<4096, 256, 0, stream>>>(O, ssb, out);
}

// Round 8
// 176.729 us; speedup vs baseline: 1.0889x; 1.0587x over previous
//
#include <hip/hip_runtime.h>
#include <hip/hip_bf16.h>
#include <stdint.h>

typedef __attribute__((ext_vector_type(8))) __bf16 bf16x8;
typedef __attribute__((ext_vector_type(4))) float  f32x4;
typedef __attribute__((ext_vector_type(16))) float f32x16;

__device__ __forceinline__ ushort f2bf(float f) {
    union { float f; uint32_t u; } v; v.f = f;
    uint32_t u = v.u;
    uint32_t r = 0x7FFFu + ((u >> 16) & 1u);
    return (ushort)((u + r) >> 16);
}
__device__ __forceinline__ float bf2f(ushort u) {
    union { uint32_t u; float f; } v; v.u = ((uint32_t)u) << 16;
    return v.f;
}
// packed RNE f32->bf16 pair (T12 recipe). Same rounding as f2bf -> bit-identical.
__device__ __forceinline__ unsigned cvtpk(float lo, float hi) {
    unsigned r;
    asm("v_cvt_pk_bf16_f32 %0, %1, %2" : "=v"(r) : "v"(lo), "v"(hi));
    return r;
}

// async global->LDS, 16B per lane; LDS dest must be wave-uniform base + lane*16
typedef __attribute__((address_space(3))) uint32_t lds_u32_t;
typedef const __attribute__((address_space(1))) uint32_t glb_u32_t;
__device__ __forceinline__ void async_copy16(const void* g, void* l) {
    __builtin_amdgcn_global_load_lds((glb_u32_t*)g, (lds_u32_t*)l, 16, 0, 0);
}

// ---- fused independent pre-work: mask (blocks 0..511) + convert (512..7679)
//      + ssb zero (block 7680). mask and convert have no data dependency; fusing
//      them overlaps VALU/L2-bound lm-GEMM+gather with HBM-bound fp32->bf16
//      streaming and removes 2 dispatch gaps. Whole blocks take one path.
__global__ __launch_bounds__(256) void prework(
    const float* __restrict__ x, const float* __restrict__ wk,
    const float* __restrict__ wq, const float* __restrict__ wv,
    ushort* __restrict__ xb, ushort* __restrict__ wball,
    const float* __restrict__ m1, const float* __restrict__ m2,
    const int* __restrict__ rb, ushort* __restrict__ gth,
    float* __restrict__ ssb)
{
    __shared__ float As8[64 * 8];     // m1[m][r][s0..s0+7]    2 KB
    __shared__ float lmS[8 * 1024];   // lm rows               32 KB
    const int tid = threadIdx.x;

    if (blockIdx.x < 512) {
        // ---------------- mask path ----------------
        // lm[m,s,u] = sum_r m1[m,r,s]*m2[m,r,u]; gth = bf16(lm[.,.,rb]*0.125)
        const int s0 = (blockIdx.x & 127) * 8;
        const int m = blockIdx.x >> 7;

        if (tid < 128) {
            int r = tid >> 1, half = tid & 1;
            *(float4*)&As8[r * 8 + half * 4] =
                *(const float4*)&m1[(m * 64 + r) * 1024 + s0 + half * 4];
        }
        __syncthreads();

        f32x4 acc8[8];
        #pragma unroll
        for (int s = 0; s < 8; s++) acc8[s] = (f32x4){0.f, 0.f, 0.f, 0.f};
        const float* m2b = m2 + m * 65536 + tid * 4;
        #pragma unroll 4
        for (int r = 0; r < 64; r++) {
            float4 b4 = *(const float4*)&m2b[r * 1024];
            f32x4 b = (f32x4){b4.x, b4.y, b4.z, b4.w};
            #pragma unroll
            for (int s = 0; s < 8; s++) {
                float a = As8[r * 8 + s];
                acc8[s] += a * b;
            }
        }
        #pragma unroll
        for (int s = 0; s < 8; s++)
            *(f32x4*)&lmS[s * 1024 + tid * 4] = acc8[s];
        __syncthreads();

        const int base = (m * 1024 + s0) * 1024;
        #pragma unroll
        for (int i = 0; i < 8; i++) {
            int c = tid + i * 256;             // 2048 int4 chunks
            int row = c >> 8, j = (c & 255) * 4;
            int4 idx = *(const int4*)&rb[base + row * 1024 + j];
            ushort4 o;
            o.x = f2bf(lmS[row * 1024 + (idx.x & 1023)] * 0.125f);
            o.y = f2bf(lmS[row * 1024 + (idx.y & 1023)] * 0.125f);
            o.z = f2bf(lmS[row * 1024 + (idx.z & 1023)] * 0.125f);
            o.w = f2bf(lmS[row * 1024 + (idx.w & 1023)] * 0.125f);
            *(ushort4*)&gth[base + row * 1024 + j] = o;
        }
    } else if (blockIdx.x < 7680) {
        // ---------------- convert path ----------------
        int i = (blockIdx.x - 512) * 256 + tid;   // 1835008 float4 chunks
        const float* src; ushort* dst; int j;
        if (i < 1048576) { src = x; dst = xb; j = i; }
        else {
            int t = i - 1048576;
            int z = t >> 18;             // 0..2
            j = t & 262143;
            src = (z == 0) ? wk : (z == 1) ? wq : wv;
            dst = wball + z * 1048576;
        }
        float4 f = ((const float4*)src)[j];
        ushort4 o;
        o.x = f2bf(f.x); o.y = f2bf(f.y); o.z = f2bf(f.z); o.w = f2bf(f.w);
        ((ushort4*)dst)[j] = o;
    } else {
        // ---------------- ssb zero ----------------
        if (tid < 64) ssb[tid] = 0.f;
    }
}

// ---------------- QKV projection GEMM: Y = X @ W^T + b ----------------
// 2-deep pipelined: BK=32, 3-deep LDS ring, raw s_barrier + counted
// s_waitcnt vmcnt(8) so 2 tiles of global_load_lds stay in flight.
// NOTE (R6 lesson): no XCD swizzle — all 768 blocks are co-resident (3/CU).
__global__ __launch_bounds__(256) void proj_gemm(
    const ushort* __restrict__ xb, const ushort* __restrict__ wball,
    const float* __restrict__ bk, const float* __restrict__ bq, const float* __restrict__ bv,
    ushort* __restrict__ kd, ushort* __restrict__ qd, ushort* __restrict__ vd)
{
    __shared__ ushort As[3 * 128 * 32];   // 24 KB, 3-deep ring
    __shared__ ushort Bs[3 * 128 * 32];   // 24 KB
    const int z = blockIdx.z;
    const int row0 = blockIdx.x * 128;
    const int col0 = blockIdx.y * 128;
    const ushort* wb = wball + z * 1048576;
    const int tid = threadIdx.x;
    const int lane = tid & 63, wave = tid >> 6;
    const int quad = lane >> 4, m15 = lane & 15;
    const int wr = wave >> 1, wc = wave & 1;

    f32x4 acc[4][4];
    for (int i = 0; i < 4; i++)
        for (int j = 0; j < 4; j++) acc[i][j] = (f32x4){0.f, 0.f, 0.f, 0.f};

#define STAGE(BI, KK) do {                                                        \
        _Pragma("unroll")                                                         \
        for (int i_ = 0; i_ < 2; i_++) {                                          \
            int c_ = tid + i_ * 256;           /* 0..511 */                       \
            int r_ = c_ >> 2, cjp_ = c_ & 3;                                      \
            int cj_ = cjp_ ^ ((r_ >> 1) & 3);                                     \
            async_copy16(&xb[(row0 + r_) * 1024 + (KK) + cj_ * 8],                \
                         &As[(BI) * 4096 + c_ * 8]);                              \
            async_copy16(&wb[(col0 + r_) * 1024 + (KK) + cj_ * 8],                \
                         &Bs[(BI) * 4096 + c_ * 8]);                              \
        }                                                                         \
    } while (0)

#define COMPUTE(BI) do {                                                          \
        const ushort* a_ = &As[(BI) * 4096];                                      \
        const ushort* b_ = &Bs[(BI) * 4096];                                      \
        bf16x8 af[4], bfv[4];                                                     \
        _Pragma("unroll")                                                         \
        for (int fr = 0; fr < 4; fr++) {                                          \
            int row = wr * 64 + fr * 16 + m15;                                    \
            af[fr] = *(const bf16x8*)&a_[row * 32 + ((quad ^ ((row >> 1) & 3)) * 8)]; \
        }                                                                         \
        _Pragma("unroll")                                                         \
        for (int fc = 0; fc < 4; fc++) {                                          \
            int row = wc * 64 + fc * 16 + m15;                                    \
            bfv[fc] = *(const bf16x8*)&b_[row * 32 + ((quad ^ ((row >> 1) & 3)) * 8)]; \
        }                                                                         \
        _Pragma("unroll")                                                         \
        for (int fr = 0; fr < 4; fr++)                                            \
            _Pragma("unroll")                                                     \
            for (int fc = 0; fc < 4; fc++)                                        \
                acc[fr][fc] = __builtin_amdgcn_mfma_f32_16x16x32_bf16(            \
                    af[fr], bfv[fc], acc[fr][fc], 0, 0, 0);                       \
    } while (0)

    STAGE(0, 0);
    STAGE(1, 32);

    int cur = 0;
    #pragma unroll 3
    for (int t = 0; t < 30; ++t) {
        int sb = cur + 2; if (sb >= 3) sb -= 3;
        STAGE(sb, (t + 2) * 32);
        asm volatile("s_waitcnt vmcnt(8)" ::: "memory");
        __builtin_amdgcn_s_barrier();
        COMPUTE(cur);
        __builtin_amdgcn_s_barrier();
        cur = (cur == 2) ? 0 : cur + 1;
    }
    asm volatile("s_waitcnt vmcnt(4)" ::: "memory");
    __builtin_amdgcn_s_barrier();
    COMPUTE(cur);
    cur = (cur == 2) ? 0 : cur + 1;
    asm volatile("s_waitcnt vmcnt(0)" ::: "memory");
    __builtin_amdgcn_s_barrier();
    COMPUTE(cur);

#undef STAGE
#undef COMPUTE

    const float* bias = (z == 0) ? bk : (z == 1) ? bq : bv;
    ushort* dstA = (z == 0) ? kd : qd;
    for (int fr = 0; fr < 4; fr++) {
        int ibase = row0 + wr * 64 + fr * 16 + quad * 4;
        int b_ = ibase >> 10, s = ibase & 1023;
        for (int fc = 0; fc < 4; fc++) {
            int j = col0 + wc * 64 + fc * 16 + m15;
            int h = j >> 6, dh = j & 63;
            float bb = bias[j];
            if (z < 2) {
                for (int r = 0; r < 4; r++)
                    dstA[((b_ * 16 + h) * 1024 + (s + r)) * 64 + dh] = f2bf(acc[fr][fc][r] + bb);
            } else {
                ushort4 o;
                o.x = f2bf(acc[fr][fc][0] + bb);
                o.y = f2bf(acc[fr][fc][1] + bb);
                o.z = f2bf(acc[fr][fc][2] + bb);
                o.w = f2bf(acc[fr][fc][3] + bb);
                *(ushort4*)&vd[((b_ * 16 + h) * 64 + dh) * 1024 + s] = o;
            }
        }
    }
}

// ---------------- fused attention: O_unnorm = (QK^T*mask) @ V ; ss = sum P^2 ----------------
// q,k: [B,H,S,64] bf16 ; v: [B,H,64,S] bf16 ; gth: [4,S,S] bf16 (scale folded in)
// Swapped QK^T (mfma(K,Q)); P in-register: mask-mult -> cvt_pk -> permlane32_swap
// -> PV A-frags. Partial O merged across wc2 pair once per block (LDS overlay).
// 2 barriers/iter; T5 setprio; mask LDS stride 76 (conflict-free b64);
// K/V/M 2-tile reg-prefetch (T14). No XCD swizzle (R6 lesson).
__global__ __launch_bounds__(256, 4) void attention(
    const ushort* __restrict__ qd, const ushort* __restrict__ kd, const ushort* __restrict__ vd,
    const ushort* __restrict__ gth, float* __restrict__ O, float* __restrict__ ss)
{
    __shared__ __align__(16) char ldsraw[28176];
    ushort* Ks  = (ushort*)ldsraw;             // [64][72]  9216 B
    ushort* Vs  = (ushort*)(ldsraw + 9216);    // [64][72]  9216 B
    ushort* Ms  = (ushort*)(ldsraw + 18432);   // [64][76]  9728 B
    float*  red = (float*)(ldsraw + 28160);    // [4]
    float*  fbuf = (float*)ldsraw;             // epilogue overlay [64][66] f32

    const int s0 = blockIdx.x * 64;
    const int bh = blockIdx.y;
    const int mm = bh & 3;
    const int tid = threadIdx.x, lane = tid & 63, wave = tid >> 6;
    const int l31 = lane & 31, hl = lane >> 5;
    const int wr2 = wave >> 1, wc2 = wave & 1;

    // per-thread staging coordinates: chunks c = tid, tid+256
    const int r0_ = tid >> 3,          o0_ = (tid & 7) * 8;
    const int r1_ = (tid + 256) >> 3,  o1_ = ((tid + 256) & 7) * 8;

    const ushort* kdb = kd + bh * 65536;        // [1024][64]
    const ushort* vdb = vd + bh * 65536;        // [64][1024]
    const ushort* gbase = gth + mm * 1048576 + s0 * 1024;   // [64 s][1024 t]

    const int srow = wr2 * 32 + l31;            // this lane's P row (s-local)
    const int tb   = wc2 * 32 + 4 * hl;         // t base within tile

    // ---- prologue: Q through Ks; tile-0 K/V/M into registers ----
    *(uint4*)&Ks[r0_ * 72 + o0_] = *(const uint4*)&qd[(bh * 1024 + s0 + r0_) * 64 + o0_];
    *(uint4*)&Ks[r1_ * 72 + o1_] = *(const uint4*)&qd[(bh * 1024 + s0 + r1_) * 64 + o1_];
    uint4 kr0 = *(const uint4*)&kdb[r0_ * 64 + o0_];
    uint4 kr1 = *(const uint4*)&kdb[r1_ * 64 + o1_];
    uint4 vr0 = *(const uint4*)&vdb[r0_ * 1024 + o0_];
    uint4 vr1 = *(const uint4*)&vdb[r1_ * 1024 + o1_];
    uint4 mr0 = *(const uint4*)&gbase[r0_ * 1024 + o0_];
    uint4 mr1 = *(const uint4*)&gbase[r1_ * 1024 + o1_];
    __syncthreads();
    bf16x8 qf[4];
    #pragma unroll
    for (int kk = 0; kk < 4; kk++)
        qf[kk] = *(const bf16x8*)&Ks[srow * 72 + kk * 16 + hl * 8];
    __syncthreads();   // qf reads done; Ks free for K tiles

    // write tile-0 regs -> LDS (M split into 2x uint2 at stride 76), issue tile-1
    *(uint4*)&Ks[r0_ * 72 + o0_] = kr0;
    *(uint4*)&Ks[r1_ * 72 + o1_] = kr1;
    *(uint4*)&Vs[r0_ * 72 + o0_] = vr0;
    *(uint4*)&Vs[r1_ * 72 + o1_] = vr1;
    *(uint2*)&Ms[r0_ * 76 + o0_]     = make_uint2(mr0.x, mr0.y);
    *(uint2*)&Ms[r0_ * 76 + o0_ + 4] = make_uint2(mr0.z, mr0.w);
    *(uint2*)&Ms[r1_ * 76 + o1_]     = make_uint2(mr1.x, mr1.y);
    *(uint2*)&Ms[r1_ * 76 + o1_ + 4] = make_uint2(mr1.z, mr1.w);
    kr0 = *(const uint4*)&kdb[(64 + r0_) * 64 + o0_];
    kr1 = *(const uint4*)&kdb[(64 + r1_) * 64 + o1_];
    vr0 = *(const uint4*)&vdb[r0_ * 1024 + 64 + o0_];
    vr1 = *(const uint4*)&vdb[r1_ * 1024 + 64 + o1_];
    mr0 = *(const uint4*)&gbase[r0_ * 1024 + 64 + o0_];
    mr1 = *(const uint4*)&gbase[r1_ * 1024 + 64 + o1_];
    __syncthreads();   // tile 0 visible

    f32x16 oaccA, oaccB;
    #pragma unroll
    for (int i = 0; i < 16; i++) { oaccA[i] = 0.f; oaccB[i] = 0.f; }
    float ss0 = 0.f, ss1 = 0.f, ss2 = 0.f, ss3 = 0.f;

    for (int t = 0; t < 16; ++t) {
        // QK^T swapped: A = K rows (t on regs), B = Q rows (s on lanes)
        f32x16 p;
        #pragma unroll
        for (int i = 0; i < 16; i++) p[i] = 0.f;
        __builtin_amdgcn_s_setprio(1);
        #pragma unroll
        for (int kk = 0; kk < 4; kk++) {
            bf16x8 kf = *(const bf16x8*)&Ks[(wc2 * 32 + l31) * 72 + kk * 16 + hl * 8];
            p = __builtin_amdgcn_mfma_f32_32x32x16_bf16(kf, qf[kk], p, 0, 0, 0);
        }
        __builtin_amdgcn_s_setprio(0);
        // mask-multiply (vector LDS reads), square-sum, cvt_pk pack to bf16 pairs.
        unsigned u[8];
        #pragma unroll
        for (int g = 0; g < 4; g++) {
            ushort4 mk = *(const ushort4*)&Ms[srow * 76 + tb + 8 * g];
            float pv0 = p[4 * g + 0] * bf2f(mk.x);
            float pv1 = p[4 * g + 1] * bf2f(mk.y);
            float pv2 = p[4 * g + 2] * bf2f(mk.z);
            float pv3 = p[4 * g + 3] * bf2f(mk.w);
            ss0 += pv0 * pv0; ss1 += pv1 * pv1;
            ss2 += pv2 * pv2; ss3 += pv3 * pv3;
            u[2 * g]     = cvtpk(pv0, pv1);
            u[2 * g + 1] = cvtpk(pv2, pv3);
        }
        // lane-pair (l31, hl=0/1) t-quad exchange: one swap fills two frag slots.
        auto r02 = __builtin_amdgcn_permlane32_swap(u[0], u[2], false, false);
        auto r13 = __builtin_amdgcn_permlane32_swap(u[1], u[3], false, false);
        auto r46 = __builtin_amdgcn_permlane32_swap(u[4], u[6], false, false);
        auto r57 = __builtin_amdgcn_permlane32_swap(u[5], u[7], false, false);
        union { unsigned q[4]; bf16x8 v; } af0, af1;
        af0.q[0] = r02[0]; af0.q[1] = r13[0]; af0.q[2] = r02[1]; af0.q[3] = r13[1];
        af1.q[0] = r46[0]; af1.q[1] = r57[0]; af1.q[2] = r46[1]; af1.q[3] = r57[1];
        // PV over this wave's t-half: partial O for all 64 dh (2 halves)
        __builtin_amdgcn_s_setprio(1);
        {
            const ushort* vrA = &Vs[l31 * 72 + wc2 * 32];
            bf16x8 b00 = *(const bf16x8*)&vrA[hl * 8];
            bf16x8 b01 = *(const bf16x8*)&vrA[16 + hl * 8];
            oaccA = __builtin_amdgcn_mfma_f32_32x32x16_bf16(af0.v, b00, oaccA, 0, 0, 0);
            oaccA = __builtin_amdgcn_mfma_f32_32x32x16_bf16(af1.v, b01, oaccA, 0, 0, 0);
            const ushort* vrB = &Vs[(32 + l31) * 72 + wc2 * 32];
            bf16x8 b10 = *(const bf16x8*)&vrB[hl * 8];
            bf16x8 b11 = *(const bf16x8*)&vrB[16 + hl * 8];
            oaccB = __builtin_amdgcn_mfma_f32_32x32x16_bf16(af0.v, b10, oaccB, 0, 0, 0);
            oaccB = __builtin_amdgcn_mfma_f32_32x32x16_bf16(af1.v, b11, oaccB, 0, 0, 0);
        }
        __builtin_amdgcn_s_setprio(0);
        __syncthreads();   // all LDS reads of tile t done; safe to overwrite
        if (t < 15) {
            *(uint4*)&Ks[r0_ * 72 + o0_] = kr0;
            *(uint4*)&Ks[r1_ * 72 + o1_] = kr1;
            *(uint4*)&Vs[r0_ * 72 + o0_] = vr0;
            *(uint4*)&Vs[r1_ * 72 + o1_] = vr1;
            *(uint2*)&Ms[r0_ * 76 + o0_]     = make_uint2(mr0.x, mr0.y);
            *(uint2*)&Ms[r0_ * 76 + o0_ + 4] = make_uint2(mr0.z, mr0.w);
            *(uint2*)&Ms[r1_ * 76 + o1_]     = make_uint2(mr1.x, mr1.y);
            *(uint2*)&Ms[r1_ * 76 + o1_ + 4] = make_uint2(mr1.z, mr1.w);
            if (t < 14) {
                const int tn = (t + 2) * 64;
                kr0 = *(const uint4*)&kdb[(tn + r0_) * 64 + o0_];
                kr1 = *(const uint4*)&kdb[(tn + r1_) * 64 + o1_];
                vr0 = *(const uint4*)&vdb[r0_ * 1024 + tn + o0_];
                vr1 = *(const uint4*)&vdb[r1_ * 1024 + tn + o1_];
                mr0 = *(const uint4*)&gbase[r0_ * 1024 + tn + o0_];
                mr1 = *(const uint4*)&gbase[r1_ * 1024 + tn + o1_];
            }
            __syncthreads();   // tile t+1 visible
        }
    }

    // ---- epilogue: merge partial O across the wc2 wave pair (once per block) ----
    if (wc2 == 1) {
        #pragma unroll
        for (int reg = 0; reg < 16; reg++) {
            int row = wr2 * 32 + (reg & 3) + 8 * (reg >> 2) + 4 * hl;
            fbuf[row * 66 + l31]      = oaccA[reg];
            fbuf[row * 66 + 32 + l31] = oaccB[reg];
        }
    }
    __syncthreads();
    if (wc2 == 0) {
        #pragma unroll
        for (int reg = 0; reg < 16; reg++) {
            int rl = (reg & 3) + 8 * (reg >> 2) + 4 * hl;
            int s = s0 + wr2 * 32 + rl;
            float a = oaccA[reg] + fbuf[(wr2 * 32 + rl) * 66 + l31];
            float b = oaccB[reg] + fbuf[(wr2 * 32 + rl) * 66 + 32 + l31];
            O[(bh * 1024 + s) * 64 + l31]      = a;
            O[(bh * 1024 + s) * 64 + 32 + l31] = b;
        }
    }
    float ssacc = (ss0 + ss1) + (ss2 + ss3);
    for (int off = 32; off; off >>= 1) ssacc += __shfl_down(ssacc, off, 64);
    if (lane == 0) red[wave] = ssacc;
    __syncthreads();
    if (tid == 0) atomicAdd(&ss[bh], red[0] + red[1] + red[2] + red[3]);
}

// ---------------- normalize + transpose to [B,S,H,DH] ----------------
__global__ __launch_bounds__(256) void normalize_out(const float* __restrict__ O,
                                                     const float* __restrict__ ss,
                                                     float* __restrict__ out)
{
    int gid = blockIdx.x * 256 + threadIdx.x;
    int e = gid * 4;
    int bh = e >> 16;
    float inv = 1.f / (sqrtf(ss[bh]) + 1e-8f);
    float4 v4 = *(const float4*)&O[e];
    int b_ = bh >> 4, h = bh & 15;
    int s = (e >> 6) & 1023, dh = e & 63;
    float4 o4 = {v4.x * inv, v4.y * inv, v4.z * inv, v4.w * inv};
    *(float4*)&out[((b_ * 1024 + s) * 16 + h) * 64 + dh] = o4;
}

extern "C" void kernel_launch(void* const* d_in, const int* in_sizes, int n_in,
                              void* d_out, int out_size, void* d_ws, size_t ws_size,
                              hipStream_t stream) {
    const float* x  = (const float*)d_in[0];
    const float* Wk = (const float*)d_in[1];
    const float* bk = (const float*)d_in[2];
    const float* Wq = (const float*)d_in[3];
    const float* bq = (const float*)d_in[4];
    const float* Wv = (const float*)d_in[5];
    const float* bv = (const float*)d_in[6];
    const float* m1 = (const float*)d_in[7];
    const float* m2 = (const float*)d_in[8];
    const int*   rb = (const int*)d_in[9];
    float* out = (float*)d_out;

    char* ws = (char*)d_ws;
    ushort* xb    = (ushort*)(ws);                  //  8 MB  [4096,1024] bf16
    ushort* wball = (ushort*)(ws + 8388608);        //  6 MB  3x[1024,1024] bf16
    ushort* kd    = (ushort*)(ws + 14680064);       //  8 MB  [B,H,S,DH] bf16
    ushort* qd    = (ushort*)(ws + 23068672);       //  8 MB
    ushort* vd    = (ushort*)(ws + 31457280);       //  8 MB  [B,H,DH,S] bf16
    float*  O     = (float*)(ws + 39845888);        // 16 MB  [B,H,S,DH] f32
    ushort* gth   = (ushort*)(ws + 56623104);       //  8 MB  [M,S,S] bf16
    float*  ssb   = (float*)(ws + 65011712);        // 64 f32

    prework<<<7681, 256, 0, stream>>>(x, Wk, Wq, Wv, xb, wball, m1, m2, rb, gth, ssb);
    proj_gemm<<<dim3(32, 8, 3), 256, 0, stream>>>(xb, wball, bk, bq, bv, kd, qd, vd);
    attention<<<dim3(16, 64), 256, 0, stream>>>(qd, kd, vd, gth, O, ssb);
    normalize_out<<<4096, 256, 0, stream>>>(O, ssb, out);
}